// Round 2
// baseline (2927.012 us; speedup 1.0000x reference)
//
#include <hip/hip_runtime.h>
#include <hip/hip_bf16.h>

#define N_NODES 50000
#define FEAT    128
#define FP_LEN  2048
#define RADIUS  4
#define N_EDGES 600000
#define BN_EPS  1e-5f
#define SM_ROWS 16

// ---------------------------------------------------------------------------
// Zero accumulators: fp (d_out), BN stats (4 layers x [sum|sumsq] x 128),
// CSR counts + cursor.
// ---------------------------------------------------------------------------
__global__ __launch_bounds__(256) void k_zero(float* fp, float* stats,
                                              int* counts, int* cursor) {
    int i = blockIdx.x * blockDim.x + threadIdx.x;
    int n = gridDim.x * blockDim.x;
    for (int j = i; j < FP_LEN; j += n) fp[j] = 0.f;
    for (int j = i; j < RADIUS * 2 * FEAT; j += n) stats[j] = 0.f;
    for (int j = i; j < N_NODES; j += n) { counts[j] = 0; cursor[j] = 0; }
}

// ---------------------------------------------------------------------------
// CSR build: histogram of dst, exclusive scan, bucket fill.
// ---------------------------------------------------------------------------
__global__ __launch_bounds__(256) void k_count(const int* __restrict__ dst,
                                               int* __restrict__ counts) {
    int e = blockIdx.x * 256 + threadIdx.x;
    if (e < N_EDGES) {
        unsigned d = (unsigned)dst[e];
        if (d < N_NODES) atomicAdd(&counts[d], 1);
    }
}

__global__ __launch_bounds__(1024) void k_scan(const int* __restrict__ counts,
                                               int* __restrict__ offs) {
    __shared__ int part[1024];
    int tid = threadIdx.x;
    const int chunk = (N_NODES + 1023) / 1024;  // 49
    int lo = tid * chunk;
    int hi = min(lo + chunk, N_NODES);
    int s = 0;
    for (int i = lo; i < hi; i++) s += counts[i];
    part[tid] = s;
    __syncthreads();
    for (int off = 1; off < 1024; off <<= 1) {
        int v = (tid >= off) ? part[tid - off] : 0;
        __syncthreads();
        part[tid] += v;
        __syncthreads();
    }
    int run = part[tid] - s;  // exclusive prefix of this chunk
    for (int i = lo; i < hi; i++) { offs[i] = run; run += counts[i]; }
    if (lo < N_NODES && hi == N_NODES) offs[N_NODES] = run;
}

__global__ __launch_bounds__(256) void k_fill(const int* __restrict__ src,
                                              const int* __restrict__ dst,
                                              const int* __restrict__ offs,
                                              int* __restrict__ cursor,
                                              int* __restrict__ csr) {
    int e = blockIdx.x * 256 + threadIdx.x;
    if (e < N_EDGES) {
        unsigned d = (unsigned)dst[e];
        unsigned s = (unsigned)src[e];
        if (d < N_NODES && s < N_NODES) {
            int p = atomicAdd(&cursor[d], 1);
            csr[offs[d] + p] = (int)s;
        }
    }
}

// ---------------------------------------------------------------------------
// Aggregation: agg[i] = feats[i] + sum_{e: dst==i} feats[src_e]
// One wave per node, float2 per lane (128 feats = 64 lanes x 2).
// ---------------------------------------------------------------------------
__global__ __launch_bounds__(256) void k_agg(const float* __restrict__ feats,
                                             float* __restrict__ agg,
                                             const int* __restrict__ offs,
                                             const int* __restrict__ csr) {
    int node = blockIdx.x * 4 + (threadIdx.x >> 6);
    int lane = threadIdx.x & 63;
    const float2* f2 = (const float2*)feats;
    float2 acc = f2[node * 64 + lane];  // self term
    int j0 = offs[node], j1 = offs[node + 1];
    for (int j = j0; j < j1; j++) {
        int s = csr[j];
        float2 v = f2[s * 64 + lane];
        acc.x += v.x; acc.y += v.y;
    }
    ((float2*)agg)[node * 64 + lane] = acc;
}

// ---------------------------------------------------------------------------
// Hash layer: h = relu(agg @ W + b), fused BN batch-stat partials.
// Block: 64 rows x 128 cols, 256 threads. Thread: 16 rows x 2 cols.
// ---------------------------------------------------------------------------
__global__ __launch_bounds__(256) void k_hash(const float* __restrict__ agg,
                                              const float* __restrict__ W,
                                              const float* __restrict__ bias,
                                              float* __restrict__ h,
                                              float* __restrict__ stat_sum,
                                              float* __restrict__ stat_sq) {
    __shared__ float Alds[64 * 128];  // 32 KB
    int t = threadIdx.x;
    int row0 = blockIdx.x * 64;

    // Stage A tile (zero-fill OOB rows); contiguous -> coalesced, conflict-free
    const float4* A4 = (const float4*)(agg + (size_t)row0 * FEAT);
    float4* L4 = (float4*)Alds;
    #pragma unroll
    for (int i = 0; i < 8; i++) {
        int idx = t + i * 256;          // float4 index within tile (2048 total)
        int r = idx >> 5;               // 32 float4 per row
        if (row0 + r < N_NODES) L4[idx] = A4[idx];
        else L4[idx] = make_float4(0.f, 0.f, 0.f, 0.f);
    }
    __syncthreads();

    int cg = t & 63;        // col group -> cols 2*cg, 2*cg+1
    int rg = t >> 6;        // row group (wave id) -> rows rg*16 .. rg*16+15
    int c0 = cg * 2;

    float acc[16][2];
    #pragma unroll
    for (int r = 0; r < 16; r++) { acc[r][0] = 0.f; acc[r][1] = 0.f; }

    #pragma unroll 4
    for (int kk = 0; kk < FEAT; kk++) {
        float2 b = ((const float2*)(W + (size_t)kk * FEAT))[cg];
        #pragma unroll
        for (int r = 0; r < 16; r++) {
            float a = Alds[(rg * 16 + r) * FEAT + kk];  // wave-uniform broadcast
            acc[r][0] += a * b.x;
            acc[r][1] += a * b.y;
        }
    }

    float b0 = bias[c0], b1 = bias[c0 + 1];
    float ps0 = 0.f, ps1 = 0.f, pq0 = 0.f, pq1 = 0.f;
    float2* H2 = (float2*)h;
    #pragma unroll
    for (int r = 0; r < 16; r++) {
        int row = row0 + rg * 16 + r;
        if (row < N_NODES) {
            float v0 = fmaxf(acc[r][0] + b0, 0.f);
            float v1 = fmaxf(acc[r][1] + b1, 0.f);
            H2[(size_t)row * 64 + cg] = make_float2(v0, v1);
            ps0 += v0; ps1 += v1;
            pq0 += v0 * v0; pq1 += v1 * v1;
        }
    }

    // Block-reduce column partials, then one atomic per column.
    __syncthreads();
    float* red = Alds;  // reuse: [4][128] sums, [4][128] sumsqs
    red[rg * FEAT + c0]     = ps0;
    red[rg * FEAT + c0 + 1] = ps1;
    red[512 + rg * FEAT + c0]     = pq0;
    red[512 + rg * FEAT + c0 + 1] = pq1;
    __syncthreads();
    if (t < FEAT) {
        float s = red[t] + red[FEAT + t] + red[2 * FEAT + t] + red[3 * FEAT + t];
        float q = red[512 + t] + red[512 + FEAT + t] + red[512 + 2 * FEAT + t] +
                  red[512 + 3 * FEAT + t];
        atomicAdd(&stat_sum[t], s);
        atomicAdd(&stat_sq[t], q);
    }
}

// ---------------------------------------------------------------------------
// BN finalize: stats -> (scale, shift) in place.
// ---------------------------------------------------------------------------
__global__ void k_finalize(float* stat_sum, float* stat_sq,
                           const float* __restrict__ gamma,
                           const float* __restrict__ beta) {
    int c = threadIdx.x;  // 128 threads
    float mu = stat_sum[c] * (1.f / N_NODES);
    float var = stat_sq[c] * (1.f / N_NODES) - mu * mu;
    float sc = gamma[c] * rsqrtf(var + BN_EPS);
    float sh = beta[c] - mu * sc;
    stat_sum[c] = sc;
    stat_sq[c] = sh;
}

// ---------------------------------------------------------------------------
// BN apply (in place): h = h*scale + shift  (per column)
// ---------------------------------------------------------------------------
__global__ __launch_bounds__(256) void k_bnapply(float* __restrict__ h,
                                                 const float* __restrict__ scale,
                                                 const float* __restrict__ shift) {
    int i = blockIdx.x * 256 + threadIdx.x;  // float4 index; 50000*32 total
    const float4* sc4 = (const float4*)scale;
    const float4* sh4 = (const float4*)shift;
    if (i < N_NODES * 32) {
        float4 v = ((float4*)h)[i];
        int cb = i & 31;
        float4 s = sc4[cb], b = sh4[cb];
        v.x = v.x * s.x + b.x;
        v.y = v.y * s.y + b.y;
        v.z = v.z * s.z + b.z;
        v.w = v.w * s.w + b.w;
        ((float4*)h)[i] = v;
    }
}

// ---------------------------------------------------------------------------
// Fused softmax-sum GEMM: fp[j] += sum_rows softmax(X @ W + b)[row][j]
// Block: 16 rows x 2048 cols, 256 threads. Thread: 16 rows x 8 cols
// (cols t*4..t*4+3 and 1024+t*4..1024+t*4+3 -> coalesced W float4 loads).
// Logits live entirely in registers; W prefetched 1 iter ahead.
// ---------------------------------------------------------------------------
__global__ __launch_bounds__(256) void k_smgemm(const float* __restrict__ X,
                                                const float* __restrict__ W,
                                                const float* __restrict__ bias,
                                                float* __restrict__ fp) {
    __shared__ float Alds[SM_ROWS * FEAT];  // 8 KB
    __shared__ float red[4 * SM_ROWS];      // per-wave row partials
    int t = threadIdx.x;
    int row0 = blockIdx.x * SM_ROWS;

    // Stage A tile: 2048 floats = 512 float4 -> 2 per thread, contiguous
    const float4* X4 = (const float4*)(X + (size_t)row0 * FEAT);
    ((float4*)Alds)[t]       = X4[t];
    ((float4*)Alds)[256 + t] = X4[256 + t];
    __syncthreads();

    float L[SM_ROWS][8];
    #pragma unroll
    for (int r = 0; r < SM_ROWS; r++)
        #pragma unroll
        for (int c = 0; c < 8; c++) L[r][c] = 0.f;

    const float4* W4 = (const float4*)W;  // row stride = 512 float4
    float4 nb0 = W4[t];
    float4 nb1 = W4[256 + t];
    for (int kk = 0; kk < FEAT; kk++) {
        float4 b0 = nb0, b1 = nb1;
        int nk = (kk + 1) & 127;  // wraps to row 0 on last iter (always valid)
        nb0 = W4[(size_t)nk * 512 + t];
        nb1 = W4[(size_t)nk * 512 + 256 + t];
        float a[SM_ROWS];
        #pragma unroll
        for (int r = 0; r < SM_ROWS; r++) a[r] = Alds[r * FEAT + kk];  // broadcast
        #pragma unroll
        for (int r = 0; r < SM_ROWS; r++) {
            L[r][0] += a[r] * b0.x; L[r][1] += a[r] * b0.y;
            L[r][2] += a[r] * b0.z; L[r][3] += a[r] * b0.w;
            L[r][4] += a[r] * b1.x; L[r][5] += a[r] * b1.y;
            L[r][6] += a[r] * b1.z; L[r][7] += a[r] * b1.w;
        }
    }

    // Bias
    float4 bb0 = ((const float4*)bias)[t];
    float4 bb1 = ((const float4*)bias)[256 + t];
    #pragma unroll
    for (int r = 0; r < SM_ROWS; r++) {
        L[r][0] += bb0.x; L[r][1] += bb0.y; L[r][2] += bb0.z; L[r][3] += bb0.w;
        L[r][4] += bb1.x; L[r][5] += bb1.y; L[r][6] += bb1.z; L[r][7] += bb1.w;
    }

    int wave = t >> 6, lane = t & 63;

    // Row max: per-thread -> wave shuffle -> cross-wave via LDS
    float m[SM_ROWS];
    #pragma unroll
    for (int r = 0; r < SM_ROWS; r++) {
        float tm = L[r][0];
        #pragma unroll
        for (int c = 1; c < 8; c++) tm = fmaxf(tm, L[r][c]);
        #pragma unroll
        for (int off = 32; off >= 1; off >>= 1)
            tm = fmaxf(tm, __shfl_xor(tm, off));
        if (lane == 0) red[wave * SM_ROWS + r] = tm;
    }
    __syncthreads();
    #pragma unroll
    for (int r = 0; r < SM_ROWS; r++)
        m[r] = fmaxf(fmaxf(red[r], red[SM_ROWS + r]),
                     fmaxf(red[2 * SM_ROWS + r], red[3 * SM_ROWS + r]));
    __syncthreads();  // all reads of max partials done before reuse

    // exp + row sum
    float invZ[SM_ROWS];
    #pragma unroll
    for (int r = 0; r < SM_ROWS; r++) {
        float s = 0.f;
        #pragma unroll
        for (int c = 0; c < 8; c++) {
            L[r][c] = __expf(L[r][c] - m[r]);
            s += L[r][c];
        }
        #pragma unroll
        for (int off = 32; off >= 1; off >>= 1)
            s += __shfl_xor(s, off);
        if (lane == 0) red[wave * SM_ROWS + r] = s;
    }
    __syncthreads();
    #pragma unroll
    for (int r = 0; r < SM_ROWS; r++) {
        float Z = red[r] + red[SM_ROWS + r] + red[2 * SM_ROWS + r] +
                  red[3 * SM_ROWS + r];
        invZ[r] = 1.f / Z;
    }

    // fp[j] += sum_r exp(l)/Z  — one atomic per (thread, col)
    #pragma unroll
    for (int c = 0; c < 4; c++) {
        float v = 0.f;
        #pragma unroll
        for (int r = 0; r < SM_ROWS; r++) v += L[r][c] * invZ[r];
        atomicAdd(&fp[t * 4 + c], v);
    }
    #pragma unroll
    for (int c = 4; c < 8; c++) {
        float v = 0.f;
        #pragma unroll
        for (int r = 0; r < SM_ROWS; r++) v += L[r][c] * invZ[r];
        atomicAdd(&fp[1024 + t * 4 + (c - 4)], v);
    }
}

// ---------------------------------------------------------------------------
// Launch
// ---------------------------------------------------------------------------
extern "C" void kernel_launch(void* const* d_in, const int* in_sizes, int n_in,
                              void* d_out, int out_size, void* d_ws, size_t ws_size,
                              hipStream_t stream) {
    const float* atoms  = (const float*)d_in[0];
    const int*   eidx   = (const int*)d_in[1];
    const float* init_w = (const float*)d_in[2];
    const float* init_b = (const float*)d_in[3];
    const float* hash_w = (const float*)d_in[4];
    const float* hash_b = (const float*)d_in[5];
    const float* soft_w = (const float*)d_in[6];
    const float* soft_b = (const float*)d_in[7];
    const float* gamma  = (const float*)d_in[8];
    const float* beta   = (const float*)d_in[9];
    float* fp = (float*)d_out;

    char* ws = (char*)d_ws;
    float* F      = (float*)ws; ws += (size_t)N_NODES * FEAT * 4;  // feats/h buffer
    float* A      = (float*)ws; ws += (size_t)N_NODES * FEAT * 4;  // agg buffer
    int*   counts = (int*)ws;   ws += (size_t)N_NODES * 4;
    int*   cursor = (int*)ws;   ws += (size_t)N_NODES * 4;
    int*   offs   = (int*)ws;   ws += (size_t)(N_NODES + 4) * 4;
    int*   csr    = (int*)ws;   ws += (size_t)N_EDGES * 4;
    float* stats  = (float*)ws; ws += (size_t)RADIUS * 2 * FEAT * 4;

    const int* src = eidx;            // edge_index[0]
    const int* dst = eidx + N_EDGES;  // edge_index[1]

    k_zero<<<256, 256, 0, stream>>>(fp, stats, counts, cursor);
    k_count<<<(N_EDGES + 255) / 256, 256, 0, stream>>>(dst, counts);
    k_scan<<<1, 1024, 0, stream>>>(counts, offs);
    k_fill<<<(N_EDGES + 255) / 256, 256, 0, stream>>>(src, dst, offs, cursor, csr);

    // initial soft assignment from raw atom features
    k_smgemm<<<N_NODES / SM_ROWS, 256, 0, stream>>>(atoms, init_w, init_b, fp);

    const float* feats = atoms;
    for (int l = 0; l < RADIUS; l++) {
        k_agg<<<N_NODES / 4, 256, 0, stream>>>(feats, A, offs, csr);
        float* ss = stats + l * 2 * FEAT;
        float* sq = ss + FEAT;
        k_hash<<<(N_NODES + 63) / 64, 256, 0, stream>>>(
            A, hash_w + (size_t)l * FEAT * FEAT, hash_b + (size_t)l * FEAT,
            F, ss, sq);
        k_finalize<<<1, FEAT, 0, stream>>>(ss, sq, gamma, beta);
        k_bnapply<<<(N_NODES * 32 + 255) / 256, 256, 0, stream>>>(F, ss, sq);
        k_smgemm<<<N_NODES / SM_ROWS, 256, 0, stream>>>(
            F, soft_w + (size_t)l * FEAT * FP_LEN, soft_b + (size_t)l * FP_LEN, fp);
        feats = F;
    }
}